// Round 2
// baseline (1328.542 us; speedup 1.0000x reference)
//
#include <hip/hip_runtime.h>
#include <hip/hip_bf16.h>
#include <math.h>

#define HH 40
#define WW 40
#define CC 128
#define TT 8
#define NIMG 16           // B*T
#define NTOK 25600        // NIMG*HH*WW
#define MDIM 512
#define NHEAD 4

// ---- input transpose: x (b,c,t,y,x) fp32 -> h (n=b*8+t, y, x, c) fp32
__global__ __launch_bounds__(256) void k_transpose_in(const float* __restrict__ x,
                                                      float* __restrict__ h) {
    int i = blockIdx.x * 256 + threadIdx.x;      // grid covers exactly NTOK*CC
    int c = i & (CC - 1);
    int tokl = i >> 7;
    int n = tokl / (HH * WW);
    int rem = tokl % (HH * WW);
    int b = n >> 3, t = n & 7;
    size_t src = ((size_t)(b * CC + c) * TT + t) * (HH * WW) + rem;
    h[i] = x[src];
}

// ---- per-token layernorm over 128 channels; one 64-lane wave per token
__global__ __launch_bounds__(256) void k_ln(const float* __restrict__ src,
                                            const float* __restrict__ gamma,
                                            const float* __restrict__ beta,
                                            float* __restrict__ dst) {
    int tok = blockIdx.x * 4 + (threadIdx.x >> 6);
    int lane = threadIdx.x & 63;
    float v0 = src[(size_t)tok * CC + lane];
    float v1 = src[(size_t)tok * CC + 64 + lane];
    float s = v0 + v1, q = v0 * v0 + v1 * v1;
    #pragma unroll
    for (int o = 32; o > 0; o >>= 1) { s += __shfl_xor(s, o); q += __shfl_xor(q, o); }
    float mean = s * (1.0f / 128.0f);
    float var = q * (1.0f / 128.0f) - mean * mean;
    float inv = rsqrtf(var + 1e-5f);
    dst[(size_t)tok * CC + lane]      = (v0 - mean) * inv * gamma[lane] + beta[lane];
    dst[(size_t)tok * CC + 64 + lane] = (v1 - mean) * inv * gamma[64 + lane] + beta[64 + lane];
}

// ---- tiled fp32 GEMM: D[M,N] = A[M,K] @ W[K,N] + bias (+R). 64x64 tile, BK=16.
// Requires M%64==0, N%64==0, K%16==0 (all true here).
__global__ __launch_bounds__(256) void k_gemm(const float* __restrict__ A,
                                              const float* __restrict__ Wt,
                                              const float* __restrict__ bias,
                                              const float* __restrict__ R,
                                              float* __restrict__ D,
                                              int K, int N) {
    __shared__ __align__(16) float As[16][64];   // [k][m]
    __shared__ __align__(16) float Bs[16][64];   // [k][n]
    int tid = threadIdx.x;
    int tx = tid & 15, ty = tid >> 4;
    int m0 = blockIdx.y * 64, n0 = blockIdx.x * 64;
    float acc[4][4] = {};
    for (int k0 = 0; k0 < K; k0 += 16) {
        // A tile: 64 rows x 16 k; each thread one float4 along k
        int idx = tid * 4;
        int ar = idx >> 4, ac = idx & 15;
        const float* ap = A + (size_t)(m0 + ar) * K + k0 + ac;
        float4 av4 = *(const float4*)ap;
        As[ac + 0][ar] = av4.x; As[ac + 1][ar] = av4.y;
        As[ac + 2][ar] = av4.z; As[ac + 3][ar] = av4.w;
        // B tile: 16 k x 64 n, coalesced loads
        #pragma unroll
        for (int l = 0; l < 4; ++l) {
            int bi = tid + l * 256;
            int br = bi >> 6, bc = bi & 63;
            Bs[br][bc] = Wt[(size_t)(k0 + br) * N + n0 + bc];
        }
        __syncthreads();
        #pragma unroll
        for (int kk = 0; kk < 16; ++kk) {
            float4 a4 = *(const float4*)&As[kk][ty * 4];
            float4 b4 = *(const float4*)&Bs[kk][tx * 4];
            float aa[4] = {a4.x, a4.y, a4.z, a4.w};
            float bb[4] = {b4.x, b4.y, b4.z, b4.w};
            #pragma unroll
            for (int i = 0; i < 4; ++i)
                #pragma unroll
                for (int j = 0; j < 4; ++j)
                    acc[i][j] += aa[i] * bb[j];
        }
        __syncthreads();
    }
    #pragma unroll
    for (int i = 0; i < 4; ++i) {
        int m = m0 + ty * 4 + i;
        #pragma unroll
        for (int j = 0; j < 4; ++j) {
            int nn = n0 + tx * 4 + j;
            float v = acc[i][j] + bias[nn];
            if (R) v += R[(size_t)m * N + nn];
            D[(size_t)m * N + nn] = v;
        }
    }
}

// ---- fused 7x7 neighborhood attention, one block per query token.
// qkv layout per token: [q(4x32) | k(4x32) | v(4x32)] = 384 fp32.
__global__ __launch_bounds__(256) void k_attn(const float* __restrict__ qkv,
                                              const float* __restrict__ rpb,  // 4 x 13 x 13
                                              float* __restrict__ out) {      // NTOK x 128
    int tok = blockIdx.x;
    int n = tok / (HH * WW);
    int rem = tok % (HH * WW);
    int yq = rem / WW, xq = rem % WW;
    int sy = min(max(yq - 3, 0), HH - 7);
    int sx = min(max(xq - 3, 0), WW - 7);
    __shared__ float qs[128];
    __shared__ float lg[4][49];
    __shared__ float inv_s[4];
    int tid = threadIdx.x;
    if (tid < 128) qs[tid] = qkv[(size_t)tok * 384 + tid];
    __syncthreads();
    if (tid < 196) {
        int hd = tid / 49, j = tid - hd * 49;
        int j1 = j / 7, j2 = j - j1 * 7;
        int ky = sy + j1, kx = sx + j2;
        const float* kp = qkv + (size_t)(n * 1600 + ky * 40 + kx) * 384 + 128 + hd * 32;
        const float* qp = qs + hd * 32;
        float dot = 0.f;
        #pragma unroll
        for (int d = 0; d < 32; ++d) dot += qp[d] * kp[d];
        float bias = rpb[hd * 169 + (ky - yq + 6) * 13 + (kx - xq + 6)];
        lg[hd][j] = dot * 0.1767766952966369f + bias;   // q * dh^-0.5
    }
    __syncthreads();
    if (tid < 4) {
        float m = -1e30f;
        for (int j = 0; j < 49; ++j) m = fmaxf(m, lg[tid][j]);
        float s = 0.f;
        for (int j = 0; j < 49; ++j) { float e = expf(lg[tid][j] - m); lg[tid][j] = e; s += e; }
        inv_s[tid] = 1.0f / s;
    }
    __syncthreads();
    if (tid < 128) {
        int hd = tid >> 5;
        float acc = 0.f;
        for (int j = 0; j < 49; ++j) {
            int ky = sy + j / 7, kx = sx + j % 7;
            acc += lg[hd][j] * qkv[(size_t)(n * 1600 + ky * 40 + kx) * 384 + 256 + tid];
        }
        out[(size_t)tok * 128 + tid] = acc * inv_s[hd];
    }
}

// ---- depthwise 3x3x3 conv over (t,y,x) + bias + exact GELU. One block per
// position, 512 threads = channels.
__global__ __launch_bounds__(512) void k_dwconv(const float* __restrict__ inp,   // [16][1600][512]
                                                const float* __restrict__ w,     // [3][3][3][512]
                                                const float* __restrict__ bias,  // [512]
                                                float* __restrict__ outp) {
    int pos = blockIdx.x;
    int m = threadIdx.x;
    int n = pos / 1600, rem = pos % 1600;
    int y = rem / 40, x = rem % 40;
    int b = n >> 3, t = n & 7;
    float acc = 0.f;
    #pragma unroll
    for (int dt = 0; dt < 3; ++dt) {
        int tt = t + dt - 1;
        if (tt < 0 || tt >= 8) continue;
        #pragma unroll
        for (int dy = 0; dy < 3; ++dy) {
            int yy = y + dy - 1;
            if (yy < 0 || yy >= 40) continue;
            #pragma unroll
            for (int dx = 0; dx < 3; ++dx) {
                int xx = x + dx - 1;
                if (xx < 0 || xx >= 40) continue;
                size_t src = ((size_t)((b * 8 + tt) * 1600 + yy * 40 + xx)) * 512 + m;
                acc += inp[src] * w[((dt * 3 + dy) * 3 + dx) * 512 + m];
            }
        }
    }
    acc += bias[m];
    float gl = 0.5f * acc * (1.0f + erff(acc * 0.70710678118654752f));
    outp[(size_t)pos * 512 + m] = gl;
}

// ---- final LN + transpose to (b,c,t,y,x) fp32
__global__ __launch_bounds__(256) void k_ln_out(const float* __restrict__ src,
                                                const float* __restrict__ gamma,
                                                const float* __restrict__ beta,
                                                float* __restrict__ out) {
    int tok = blockIdx.x * 4 + (threadIdx.x >> 6);
    int lane = threadIdx.x & 63;
    float v0 = src[(size_t)tok * 128 + lane];
    float v1 = src[(size_t)tok * 128 + 64 + lane];
    float s = v0 + v1, q = v0 * v0 + v1 * v1;
    #pragma unroll
    for (int o = 32; o > 0; o >>= 1) { s += __shfl_xor(s, o); q += __shfl_xor(q, o); }
    float mean = s * (1.0f / 128.0f);
    float var = q * (1.0f / 128.0f) - mean * mean;
    float inv = rsqrtf(var + 1e-5f);
    float r0 = (v0 - mean) * inv * gamma[lane] + beta[lane];
    float r1 = (v1 - mean) * inv * gamma[64 + lane] + beta[64 + lane];
    int n = tok / 1600, rem = tok % 1600;
    int b = n >> 3, t = n & 7;
    out[((size_t)(b * 128 + lane) * 8 + t) * 1600 + rem] = r0;
    out[((size_t)(b * 128 + 64 + lane) * 8 + t) * 1600 + rem] = r1;
}

extern "C" void kernel_launch(void* const* d_in, const int* in_sizes, int n_in,
                              void* d_out, int out_size, void* d_ws, size_t ws_size,
                              hipStream_t stream) {
    const float* x      = (const float*)d_in[0];
    const float* ln1_g  = (const float*)d_in[1];
    const float* ln1_b  = (const float*)d_in[2];
    const float* qkv_w  = (const float*)d_in[3];
    const float* qkv_b  = (const float*)d_in[4];
    const float* rpb    = (const float*)d_in[5];
    const float* proj_w = (const float*)d_in[6];
    const float* proj_b = (const float*)d_in[7];
    const float* ln2_g  = (const float*)d_in[8];
    const float* ln2_b  = (const float*)d_in[9];
    const float* fc1_w  = (const float*)d_in[10];
    const float* fc1_b  = (const float*)d_in[11];
    const float* dw_w   = (const float*)d_in[12];
    const float* dw_b   = (const float*)d_in[13];
    const float* fc2_w  = (const float*)d_in[14];
    const float* fc2_b  = (const float*)d_in[15];
    const float* out_g  = (const float*)d_in[16];
    const float* out_b  = (const float*)d_in[17];
    float* out = (float*)d_out;

    // workspace layout (floats):
    //   h    : NTOK*128   residual stream
    //   lnb  : NTOK*128   LN out / attn out
    //   qkvb : NTOK*384   qkv
    //   f1   : NTOK*512   fc1+dwconv input
    //   f2   : aliases [lnb..qkvb] = NTOK*512 (dead region during dwconv/fc2)
    float* h    = (float*)d_ws;
    float* lnb  = h    + (size_t)NTOK * 128;
    float* qkvb = lnb  + (size_t)NTOK * 128;
    float* f1   = qkvb + (size_t)NTOK * 384;
    float* f2   = lnb;   // alias: lnb+qkvb = NTOK*512 contiguous, dead during dwconv/fc2

    k_transpose_in<<<NTOK * 128 / 256, 256, 0, stream>>>(x, h);
    for (int l = 0; l < 2; ++l) {
        k_ln<<<NTOK / 4, 256, 0, stream>>>(h, ln1_g + l * 128, ln1_b + l * 128, lnb);
        k_gemm<<<dim3(384 / 64, NTOK / 64), 256, 0, stream>>>(
            lnb, qkv_w + l * 128 * 384, qkv_b + l * 384, nullptr, qkvb, 128, 384);
        k_attn<<<NTOK, 256, 0, stream>>>(qkvb, rpb + l * 4 * 169, lnb);
        k_gemm<<<dim3(128 / 64, NTOK / 64), 256, 0, stream>>>(
            lnb, proj_w + l * 128 * 128, proj_b + l * 128, h, h, 128, 128);
        k_ln<<<NTOK / 4, 256, 0, stream>>>(h, ln2_g + l * 128, ln2_b + l * 128, lnb);
        k_gemm<<<dim3(512 / 64, NTOK / 64), 256, 0, stream>>>(
            lnb, fc1_w + l * 128 * 512, fc1_b + l * 512, nullptr, f1, 128, 512);
        k_dwconv<<<NTOK, 512, 0, stream>>>(f1, dw_w + l * 27 * 512, dw_b + l * 512, f2);
        k_gemm<<<dim3(128 / 64, NTOK / 64), 256, 0, stream>>>(
            f2, fc2_w + l * 512 * 128, fc2_b + l * 128, h, h, 512, 128);
    }
    k_ln_out<<<NTOK / 4, 256, 0, stream>>>(h, out_g, out_b, out);
}

// Round 3
// 851.925 us; speedup vs baseline: 1.5595x; 1.5595x over previous
//
#include <hip/hip_runtime.h>
#include <hip/hip_bf16.h>
#include <math.h>

#define HH 40
#define WW 40
#define CC 128
#define TT 8
#define NIMG 16           // B*T
#define NTOK 25600        // NIMG*HH*WW
#define MDIM 512
#define NHEAD 4
#define KW 36             // padded inner stride (floats) for K/V LDS tiles

// ---- input transpose: x (b,c,t,y,x) fp32 -> h (n=b*8+t, y, x, c) fp32
__global__ __launch_bounds__(256) void k_transpose_in(const float* __restrict__ x,
                                                      float* __restrict__ h) {
    int i = blockIdx.x * 256 + threadIdx.x;      // grid covers exactly NTOK*CC
    int c = i & (CC - 1);
    int tokl = i >> 7;
    int n = tokl / (HH * WW);
    int rem = tokl % (HH * WW);
    int b = n >> 3, t = n & 7;
    size_t src = ((size_t)(b * CC + c) * TT + t) * (HH * WW) + rem;
    h[i] = x[src];
}

// ---- per-token layernorm over 128 channels; one 64-lane wave per token
__global__ __launch_bounds__(256) void k_ln(const float* __restrict__ src,
                                            const float* __restrict__ gamma,
                                            const float* __restrict__ beta,
                                            float* __restrict__ dst) {
    int tok = blockIdx.x * 4 + (threadIdx.x >> 6);
    int lane = threadIdx.x & 63;
    float v0 = src[(size_t)tok * CC + lane];
    float v1 = src[(size_t)tok * CC + 64 + lane];
    float s = v0 + v1, q = v0 * v0 + v1 * v1;
    #pragma unroll
    for (int o = 32; o > 0; o >>= 1) { s += __shfl_xor(s, o); q += __shfl_xor(q, o); }
    float mean = s * (1.0f / 128.0f);
    float var = q * (1.0f / 128.0f) - mean * mean;
    float inv = rsqrtf(var + 1e-5f);
    dst[(size_t)tok * CC + lane]      = (v0 - mean) * inv * gamma[lane] + beta[lane];
    dst[(size_t)tok * CC + 64 + lane] = (v1 - mean) * inv * gamma[64 + lane] + beta[64 + lane];
}

// ---- tiled fp32 GEMM: D[M,N] = A[M,K] @ W[K,N] + bias (+R). 64x64 tile, BK=16.
__global__ __launch_bounds__(256) void k_gemm(const float* __restrict__ A,
                                              const float* __restrict__ Wt,
                                              const float* __restrict__ bias,
                                              const float* __restrict__ R,
                                              float* __restrict__ D,
                                              int K, int N) {
    __shared__ __align__(16) float As[16][64];   // [k][m]
    __shared__ __align__(16) float Bs[16][64];   // [k][n]
    int tid = threadIdx.x;
    int tx = tid & 15, ty = tid >> 4;
    int m0 = blockIdx.y * 64, n0 = blockIdx.x * 64;
    float acc[4][4] = {};
    for (int k0 = 0; k0 < K; k0 += 16) {
        int idx = tid * 4;
        int ar = idx >> 4, ac = idx & 15;
        const float* ap = A + (size_t)(m0 + ar) * K + k0 + ac;
        float4 av4 = *(const float4*)ap;
        As[ac + 0][ar] = av4.x; As[ac + 1][ar] = av4.y;
        As[ac + 2][ar] = av4.z; As[ac + 3][ar] = av4.w;
        #pragma unroll
        for (int l = 0; l < 4; ++l) {
            int bi = tid + l * 256;
            int br = bi >> 6, bc = bi & 63;
            Bs[br][bc] = Wt[(size_t)(k0 + br) * N + n0 + bc];
        }
        __syncthreads();
        #pragma unroll
        for (int kk = 0; kk < 16; ++kk) {
            float4 a4 = *(const float4*)&As[kk][ty * 4];
            float4 b4 = *(const float4*)&Bs[kk][tx * 4];
            float aa[4] = {a4.x, a4.y, a4.z, a4.w};
            float bb[4] = {b4.x, b4.y, b4.z, b4.w};
            #pragma unroll
            for (int i = 0; i < 4; ++i)
                #pragma unroll
                for (int j = 0; j < 4; ++j)
                    acc[i][j] += aa[i] * bb[j];
        }
        __syncthreads();
    }
    #pragma unroll
    for (int i = 0; i < 4; ++i) {
        int m = m0 + ty * 4 + i;
        #pragma unroll
        for (int j = 0; j < 4; ++j) {
            int nn = n0 + tx * 4 + j;
            float v = acc[i][j] + bias[nn];
            if (R) v += R[(size_t)m * N + nn];
            D[(size_t)m * N + nn] = v;
        }
    }
}

// ---- row-tiled 7x7 neighborhood attention.
// One block per (n, y, head): stages the 7x40x32 K and V window in LDS,
// computes all 40 queries of the row. qkv token layout: [q|k|v] = 384 fp32.
__global__ __launch_bounds__(256) void k_attn(const float* __restrict__ qkv,
                                              const float* __restrict__ rpb,  // 4 x 13 x 13
                                              float* __restrict__ out) {      // NTOK x 128
    int blk = blockIdx.x;            // ((n*40 + y)*4 + head)
    int head = blk & 3;
    int ny = blk >> 2;
    int n = ny / 40, y = ny % 40;
    int sy = min(max(y - 3, 0), HH - 7);
    __shared__ float qs[40][32];
    __shared__ float Ks[7][40][KW];
    __shared__ float Vs[7][40][KW];
    __shared__ float lg[40][49];
    int tid = threadIdx.x;
    // q (pre-scaled)
    for (int i = tid; i < 1280; i += 256) {
        int xq = i >> 5, d = i & 31;
        qs[xq][d] = qkv[((size_t)(n * 1600 + y * 40 + xq)) * 384 + head * 32 + d]
                    * 0.1767766952966369f;
    }
    // K/V window, float4 global -> float4 LDS
    for (int i4 = tid; i4 < 2240; i4 += 256) {     // 7*40*8
        int d4 = i4 & 7, kx = (i4 >> 3) % 40, ky = i4 / 320;
        size_t base = ((size_t)(n * 1600 + (sy + ky) * 40 + kx)) * 384 + head * 32 + d4 * 4;
        float4 kv = *(const float4*)(qkv + base + 128);
        float4 vv = *(const float4*)(qkv + base + 256);
        *(float4*)&Ks[ky][kx][d4 * 4] = kv;
        *(float4*)&Vs[ky][kx][d4 * 4] = vv;
    }
    __syncthreads();
    // logits + rpb
    for (int p = tid; p < 1960; p += 256) {        // 40*49
        int xq = p / 49, j = p - xq * 49;
        int ky = j / 7, jx = j - ky * 7;
        int sx = min(max(xq - 3, 0), WW - 7);
        int kx = sx + jx;
        const float* kp = &Ks[ky][kx][0];
        const float* qp = &qs[xq][0];
        float dot = 0.f;
        #pragma unroll
        for (int c = 0; c < 8; ++c) {
            float4 a = *(const float4*)(qp + 4 * c);
            float4 b = *(const float4*)(kp + 4 * c);
            dot += a.x * b.x + a.y * b.y + a.z * b.z + a.w * b.w;
        }
        lg[xq][j] = dot + rpb[head * 169 + (sy + ky - y + 6) * 13 + (kx - xq + 6)];
    }
    __syncthreads();
    // softmax, one thread per query (49 wide, serial)
    if (tid < 40) {
        float m = -1e30f;
        for (int j = 0; j < 49; ++j) m = fmaxf(m, lg[tid][j]);
        float s = 0.f;
        for (int j = 0; j < 49; ++j) { float e = expf(lg[tid][j] - m); lg[tid][j] = e; s += e; }
        float inv = 1.0f / s;
        for (int j = 0; j < 49; ++j) lg[tid][j] *= inv;
    }
    __syncthreads();
    // PV reduce
    for (int o = tid; o < 1280; o += 256) {
        int xq = o >> 5, d = o & 31;
        int sx = min(max(xq - 3, 0), WW - 7);
        float acc = 0.f;
        #pragma unroll
        for (int j = 0; j < 49; ++j) {
            acc += lg[xq][j] * Vs[j / 7][sx + j % 7][d];
        }
        out[((size_t)(n * 1600 + y * 40 + xq)) * 128 + head * 32 + d] = acc;
    }
}

// ---- depthwise 3x3x3 conv + bias + exact GELU, register-sliding window.
// One block per (n, y) row; 512 threads = channels; each thread walks x 0..39.
__global__ __launch_bounds__(512) void k_dwconv(const float* __restrict__ inp,   // [16][1600][512]
                                                const float* __restrict__ w,     // [3][3][3][512]
                                                const float* __restrict__ bias,  // [512]
                                                float* __restrict__ outp) {
    int ny = blockIdx.x;             // n*40 + y
    int n = ny / 40, y = ny - n * 40;
    int b = n >> 3, t = n & 7;
    int m = threadIdx.x;
    float wr[27];
    #pragma unroll
    for (int i = 0; i < 27; ++i) wr[i] = w[i * 512 + m];
    float bs = bias[m];
    const float* rp[9];              // row base (x=0) for each (dt,dy), or null
    #pragma unroll
    for (int dt = 0; dt < 3; ++dt)
        #pragma unroll
        for (int dy = 0; dy < 3; ++dy) {
            int tt = t + dt - 1, yy = y + dy - 1;
            bool v = (tt >= 0 && tt < 8 && yy >= 0 && yy < 40);
            rp[dt * 3 + dy] = v ? inp + ((size_t)((b * 8 + tt) * 1600 + yy * 40)) * 512 + m
                                : nullptr;
        }
    float c0[9], c1[9], c2[9];
    #pragma unroll
    for (int p = 0; p < 9; ++p) { c0[p] = 0.f; c1[p] = rp[p] ? rp[p][0] : 0.f; }
    size_t outbase = ((size_t)(n * 1600 + y * 40)) * 512 + m;
    for (int x = 0; x < 40; ++x) {
        #pragma unroll
        for (int p = 0; p < 9; ++p)
            c2[p] = (x < 39 && rp[p]) ? rp[p][(size_t)(x + 1) * 512] : 0.f;
        float acc = bs;
        #pragma unroll
        for (int p = 0; p < 9; ++p)
            acc += wr[p * 3 + 0] * c0[p] + wr[p * 3 + 1] * c1[p] + wr[p * 3 + 2] * c2[p];
        float g = 0.5f * acc * (1.0f + erff(acc * 0.70710678118654752f));
        outp[outbase + (size_t)x * 512] = g;
        #pragma unroll
        for (int p = 0; p < 9; ++p) { c0[p] = c1[p]; c1[p] = c2[p]; }
    }
}

// ---- final LN + transpose to (b,c,t,y,x) fp32
__global__ __launch_bounds__(256) void k_ln_out(const float* __restrict__ src,
                                                const float* __restrict__ gamma,
                                                const float* __restrict__ beta,
                                                float* __restrict__ out) {
    int tok = blockIdx.x * 4 + (threadIdx.x >> 6);
    int lane = threadIdx.x & 63;
    float v0 = src[(size_t)tok * 128 + lane];
    float v1 = src[(size_t)tok * 128 + 64 + lane];
    float s = v0 + v1, q = v0 * v0 + v1 * v1;
    #pragma unroll
    for (int o = 32; o > 0; o >>= 1) { s += __shfl_xor(s, o); q += __shfl_xor(q, o); }
    float mean = s * (1.0f / 128.0f);
    float var = q * (1.0f / 128.0f) - mean * mean;
    float inv = rsqrtf(var + 1e-5f);
    float r0 = (v0 - mean) * inv * gamma[lane] + beta[lane];
    float r1 = (v1 - mean) * inv * gamma[64 + lane] + beta[64 + lane];
    int n = tok / 1600, rem = tok % 1600;
    int b = n >> 3, t = n & 7;
    out[((size_t)(b * 128 + lane) * 8 + t) * 1600 + rem] = r0;
    out[((size_t)(b * 128 + 64 + lane) * 8 + t) * 1600 + rem] = r1;
}

extern "C" void kernel_launch(void* const* d_in, const int* in_sizes, int n_in,
                              void* d_out, int out_size, void* d_ws, size_t ws_size,
                              hipStream_t stream) {
    const float* x      = (const float*)d_in[0];
    const float* ln1_g  = (const float*)d_in[1];
    const float* ln1_b  = (const float*)d_in[2];
    const float* qkv_w  = (const float*)d_in[3];
    const float* qkv_b  = (const float*)d_in[4];
    const float* rpb    = (const float*)d_in[5];
    const float* proj_w = (const float*)d_in[6];
    const float* proj_b = (const float*)d_in[7];
    const float* ln2_g  = (const float*)d_in[8];
    const float* ln2_b  = (const float*)d_in[9];
    const float* fc1_w  = (const float*)d_in[10];
    const float* fc1_b  = (const float*)d_in[11];
    const float* dw_w   = (const float*)d_in[12];
    const float* dw_b   = (const float*)d_in[13];
    const float* fc2_w  = (const float*)d_in[14];
    const float* fc2_b  = (const float*)d_in[15];
    const float* out_g  = (const float*)d_in[16];
    const float* out_b  = (const float*)d_in[17];
    float* out = (float*)d_out;

    float* h    = (float*)d_ws;                    // NTOK*128 residual
    float* lnb  = h    + (size_t)NTOK * 128;       // NTOK*128 LN/attn out
    float* qkvb = lnb  + (size_t)NTOK * 128;       // NTOK*384
    float* f1   = qkvb + (size_t)NTOK * 384;       // NTOK*512
    float* f2   = lnb;   // alias: lnb+qkvb contiguous NTOK*512, dead during dwconv/fc2

    k_transpose_in<<<NTOK * 128 / 256, 256, 0, stream>>>(x, h);
    for (int l = 0; l < 2; ++l) {
        k_ln<<<NTOK / 4, 256, 0, stream>>>(h, ln1_g + l * 128, ln1_b + l * 128, lnb);
        k_gemm<<<dim3(384 / 64, NTOK / 64), 256, 0, stream>>>(
            lnb, qkv_w + l * 128 * 384, qkv_b + l * 384, nullptr, qkvb, 128, 384);
        k_attn<<<NIMG * HH * NHEAD, 256, 0, stream>>>(qkvb, rpb + l * 4 * 169, lnb);
        k_gemm<<<dim3(128 / 64, NTOK / 64), 256, 0, stream>>>(
            lnb, proj_w + l * 128 * 128, proj_b + l * 128, h, h, 128, 128);
        k_ln<<<NTOK / 4, 256, 0, stream>>>(h, ln2_g + l * 128, ln2_b + l * 128, lnb);
        k_gemm<<<dim3(512 / 64, NTOK / 64), 256, 0, stream>>>(
            lnb, fc1_w + l * 128 * 512, fc1_b + l * 512, nullptr, f1, 128, 512);
        k_dwconv<<<NIMG * HH, 512, 0, stream>>>(f1, dw_w + l * 27 * 512, dw_b + l * 512, f2);
        k_gemm<<<dim3(128 / 64, NTOK / 64), 256, 0, stream>>>(
            f2, fc2_w + l * 512 * 128, fc2_b + l * 128, h, h, 512, 128);
    }
    k_ln_out<<<NTOK / 4, 256, 0, stream>>>(h, out_g, out_b, out);
}

// Round 4
// 521.510 us; speedup vs baseline: 2.5475x; 1.6336x over previous
//
#include <hip/hip_runtime.h>
#include <hip/hip_bf16.h>
#include <math.h>

typedef __hip_bfloat16 bf16;
typedef __attribute__((ext_vector_type(8))) short short8;
typedef __attribute__((ext_vector_type(4))) float floatx4;

#define HH 40
#define WW 40
#define CC 128
#define TT 8
#define NIMG 16           // B*T
#define NTOK 25600        // NIMG*HH*WW
#define MDIM 512
#define NHEAD 4
#define KW 36             // padded inner stride (floats) for K/V LDS tile

// weight-transpose buffer offsets (bf16 elems), per layer
#define WT_QKV 0
#define WT_PROJ 49152
#define WT_FC1  65536
#define WT_FC2  131072
#define WT_L    196608

// ---- input transpose: x (b,c,t,y,x) fp32 -> h (n=b*8+t, y, x, c) fp32
__global__ __launch_bounds__(256) void k_transpose_in(const float* __restrict__ x,
                                                      float* __restrict__ h) {
    int i = blockIdx.x * 256 + threadIdx.x;
    int c = i & (CC - 1);
    int tokl = i >> 7;
    int n = tokl / (HH * WW);
    int rem = tokl % (HH * WW);
    int b = n >> 3, t = n & 7;
    size_t src = ((size_t)(b * CC + c) * TT + t) * (HH * WW) + rem;
    h[i] = x[src];
}

// ---- weight convert+transpose: W[K,N] fp32 -> Wt[N,K] bf16, 64x64 LDS tiles.
// 96 blocks: 48 per layer (qkv 12, proj 4, fc1 16, fc2 16).
__global__ __launch_bounds__(256) void k_wt(const float* __restrict__ qkv_w,
                                            const float* __restrict__ proj_w,
                                            const float* __restrict__ fc1_w,
                                            const float* __restrict__ fc2_w,
                                            bf16* __restrict__ wt) {
    __shared__ float tile[64][65];
    int id = blockIdx.x;
    int l = id / 48, r = id % 48;
    const float* src; bf16* dst; int K_, N_, t;
    if (r < 12)      { src = qkv_w  + l * 128 * 384; dst = wt + l * WT_L + WT_QKV; K_ = 128; N_ = 384; t = r; }
    else if (r < 16) { src = proj_w + l * 128 * 128; dst = wt + l * WT_L + WT_PROJ; K_ = 128; N_ = 128; t = r - 12; }
    else if (r < 32) { src = fc1_w  + l * 128 * 512; dst = wt + l * WT_L + WT_FC1; K_ = 128; N_ = 512; t = r - 16; }
    else             { src = fc2_w  + l * 512 * 128; dst = wt + l * WT_L + WT_FC2; K_ = 512; N_ = 128; t = r - 32; }
    int KT = K_ >> 6;
    int k0 = (t % KT) * 64, n0 = (t / KT) * 64;
    int tid = threadIdx.x;
    for (int c = tid; c < 4096; c += 256) {
        int kk = c >> 6, nn = c & 63;
        tile[kk][nn] = src[(size_t)(k0 + kk) * N_ + n0 + nn];
    }
    __syncthreads();
    for (int c = tid; c < 4096; c += 256) {
        int nn = c >> 6, kk = c & 63;
        dst[(size_t)(n0 + nn) * K_ + k0 + kk] = __float2bfloat16(tile[kk][nn]);
    }
}

// ---- per-token layernorm over 128 channels; one wave per token; bf16 out.
// Lane handles channels {2*lane, 2*lane+1}.
__global__ __launch_bounds__(256) void k_ln(const float* __restrict__ src,
                                            const float* __restrict__ gamma,
                                            const float* __restrict__ beta,
                                            bf16* __restrict__ dst) {
    int tok = blockIdx.x * 4 + (threadIdx.x >> 6);
    int lane = threadIdx.x & 63;
    float2 v = *(const float2*)(src + (size_t)tok * CC + 2 * lane);
    float s = v.x + v.y, q = v.x * v.x + v.y * v.y;
    #pragma unroll
    for (int o = 32; o > 0; o >>= 1) { s += __shfl_xor(s, o); q += __shfl_xor(q, o); }
    float mean = s * (1.0f / 128.0f);
    float var = q * (1.0f / 128.0f) - mean * mean;
    float inv = rsqrtf(var + 1e-5f);
    float r0 = (v.x - mean) * inv * gamma[2 * lane]     + beta[2 * lane];
    float r1 = (v.y - mean) * inv * gamma[2 * lane + 1] + beta[2 * lane + 1];
    __hip_bfloat162 o2;
    o2.x = __float2bfloat16(r0); o2.y = __float2bfloat16(r1);
    *(__hip_bfloat162*)(dst + (size_t)tok * CC + 2 * lane) = o2;
}

// ---- MFMA bf16 GEMM: D[M,N] = A[M,K] @ Bt[N,K]^T + bias (+R), fp32 out.
// A, Bt bf16 k-major. 256 threads = 4 waves.
template<int BM, int BN, int WM, int WN>
__global__ __launch_bounds__(256) void k_gemm_mfma(const bf16* __restrict__ A,
                                                   const bf16* __restrict__ Bt,
                                                   const float* __restrict__ bias,
                                                   const float* __restrict__ R,
                                                   float* __restrict__ D,
                                                   int K, int N) {
    constexpr int LDK = 40;                 // bf16 row stride (80 B): 2-way banks, 16B aligned
    __shared__ bf16 As[BM * LDK];
    __shared__ bf16 Bs[BN * LDK];
    int tid = threadIdx.x;
    int wave = tid >> 6, lane = tid & 63;
    int l15 = lane & 15, quad = lane >> 4;
    constexpr int WCOLS = BN / WN;
    int wr = wave / WCOLS, wc = wave % WCOLS;
    int m0 = blockIdx.y * BM, n0 = blockIdx.x * BN;
    constexpr int MI = WM / 16, NJ = WN / 16;
    floatx4 acc[MI][NJ];
    #pragma unroll
    for (int i = 0; i < MI; ++i)
        #pragma unroll
        for (int j = 0; j < NJ; ++j)
            acc[i][j] = (floatx4){0.f, 0.f, 0.f, 0.f};

    for (int k0 = 0; k0 < K; k0 += 32) {
        #pragma unroll
        for (int c = tid; c < BM * 4; c += 256) {
            int row = c >> 2, off = (c & 3) * 8;
            *(uint4*)&As[row * LDK + off] =
                *(const uint4*)&A[(size_t)(m0 + row) * K + k0 + off];
        }
        #pragma unroll
        for (int c = tid; c < BN * 4; c += 256) {
            int row = c >> 2, off = (c & 3) * 8;
            *(uint4*)&Bs[row * LDK + off] =
                *(const uint4*)&Bt[(size_t)(n0 + row) * K + k0 + off];
        }
        __syncthreads();
        short8 af[MI], bfr[NJ];
        #pragma unroll
        for (int i = 0; i < MI; ++i)
            af[i] = *(const short8*)&As[(wr * WM + i * 16 + l15) * LDK + quad * 8];
        #pragma unroll
        for (int j = 0; j < NJ; ++j)
            bfr[j] = *(const short8*)&Bs[(wc * WN + j * 16 + l15) * LDK + quad * 8];
        #pragma unroll
        for (int i = 0; i < MI; ++i)
            #pragma unroll
            for (int j = 0; j < NJ; ++j)
                acc[i][j] = __builtin_amdgcn_mfma_f32_16x16x32_bf16(af[i], bfr[j], acc[i][j], 0, 0, 0);
        __syncthreads();
    }
    // epilogue: C/D map col=lane&15, row=quad*4+reg
    #pragma unroll
    for (int i = 0; i < MI; ++i) {
        #pragma unroll
        for (int j = 0; j < NJ; ++j) {
            int nn = n0 + wc * WN + j * 16 + l15;
            float bv = bias[nn];
            #pragma unroll
            for (int rg = 0; rg < 4; ++rg) {
                int m = m0 + wr * WM + i * 16 + quad * 4 + rg;
                float v = acc[i][j][rg] + bv;
                if (R) v += R[(size_t)m * N + nn];
                D[(size_t)m * N + nn] = v;
            }
        }
    }
}

// ---- row-tiled 7x7 neighborhood attention, two-phase K/V staging, bf16 out.
__global__ __launch_bounds__(256) void k_attn(const float* __restrict__ qkv,
                                              const float* __restrict__ rpb,
                                              bf16* __restrict__ out) {
    int blk = blockIdx.x;            // ((n*40 + y)*4 + head)
    int head = blk & 3;
    int ny = blk >> 2;
    int n = ny / 40, y = ny % 40;
    int sy = min(max(y - 3, 0), HH - 7);
    __shared__ float qs[40][32];
    __shared__ float KVs[7][40][KW];
    __shared__ float lg[40][49];
    int tid = threadIdx.x;
    for (int i = tid; i < 1280; i += 256) {
        int xq = i >> 5, d = i & 31;
        qs[xq][d] = qkv[((size_t)(n * 1600 + y * 40 + xq)) * 384 + head * 32 + d]
                    * 0.1767766952966369f;
    }
    // phase 1: K window
    for (int i4 = tid; i4 < 2240; i4 += 256) {     // 7*40*8
        int d4 = i4 & 7, kx = (i4 >> 3) % 40, ky = i4 / 320;
        size_t base = ((size_t)(n * 1600 + (sy + ky) * 40 + kx)) * 384 + head * 32 + d4 * 4;
        *(float4*)&KVs[ky][kx][d4 * 4] = *(const float4*)(qkv + base + 128);
    }
    __syncthreads();
    for (int p = tid; p < 1960; p += 256) {        // 40*49 logits
        int xq = p / 49, j = p - xq * 49;
        int ky = j / 7, jx = j - ky * 7;
        int sx = min(max(xq - 3, 0), WW - 7);
        int kx = sx + jx;
        const float* kp = &KVs[ky][kx][0];
        const float* qp = &qs[xq][0];
        float dot = 0.f;
        #pragma unroll
        for (int c = 0; c < 8; ++c) {
            float4 a = *(const float4*)(qp + 4 * c);
            float4 b = *(const float4*)(kp + 4 * c);
            dot += a.x * b.x + a.y * b.y + a.z * b.z + a.w * b.w;
        }
        lg[xq][j] = dot + rpb[head * 169 + (sy + ky - y + 6) * 13 + (kx - xq + 6)];
    }
    __syncthreads();                               // logits done, K reads done
    // phase 2: overwrite with V; also softmax (tid<40) — disjoint LDS regions
    for (int i4 = tid; i4 < 2240; i4 += 256) {
        int d4 = i4 & 7, kx = (i4 >> 3) % 40, ky = i4 / 320;
        size_t base = ((size_t)(n * 1600 + (sy + ky) * 40 + kx)) * 384 + head * 32 + d4 * 4;
        *(float4*)&KVs[ky][kx][d4 * 4] = *(const float4*)(qkv + base + 256);
    }
    if (tid < 40) {
        float m = -1e30f;
        for (int j = 0; j < 49; ++j) m = fmaxf(m, lg[tid][j]);
        float s = 0.f;
        for (int j = 0; j < 49; ++j) { float e = expf(lg[tid][j] - m); lg[tid][j] = e; s += e; }
        float inv = 1.0f / s;
        for (int j = 0; j < 49; ++j) lg[tid][j] *= inv;
    }
    __syncthreads();
    // PV reduce: 2 channels per thread, bf16x2 store
    for (int o = tid; o < 640; o += 256) {
        int xq = o >> 4, dp = (o & 15) * 2;
        int sx = min(max(xq - 3, 0), WW - 7);
        float a0 = 0.f, a1 = 0.f;
        #pragma unroll
        for (int j = 0; j < 49; ++j) {
            float p = lg[xq][j];
            const float* vp = &KVs[j / 7][sx + j % 7][dp];
            a0 += p * vp[0]; a1 += p * vp[1];
        }
        __hip_bfloat162 o2;
        o2.x = __float2bfloat16(a0); o2.y = __float2bfloat16(a1);
        *(__hip_bfloat162*)(out + ((size_t)(n * 1600 + y * 40 + xq)) * 128 + head * 32 + dp) = o2;
    }
}

// ---- depthwise 3x3x3 conv + bias + exact GELU, register-sliding window, bf16 out.
__global__ __launch_bounds__(512) void k_dwconv(const float* __restrict__ inp,
                                                const float* __restrict__ w,
                                                const float* __restrict__ bias,
                                                bf16* __restrict__ outp) {
    int ny = blockIdx.x;             // n*40 + y
    int n = ny / 40, y = ny - n * 40;
    int b = n >> 3, t = n & 7;
    int m = threadIdx.x;
    float wr[27];
    #pragma unroll
    for (int i = 0; i < 27; ++i) wr[i] = w[i * 512 + m];
    float bs = bias[m];
    const float* rp[9];
    #pragma unroll
    for (int dt = 0; dt < 3; ++dt)
        #pragma unroll
        for (int dy = 0; dy < 3; ++dy) {
            int tt = t + dt - 1, yy = y + dy - 1;
            bool v = (tt >= 0 && tt < 8 && yy >= 0 && yy < 40);
            rp[dt * 3 + dy] = v ? inp + ((size_t)((b * 8 + tt) * 1600 + yy * 40)) * 512 + m
                                : nullptr;
        }
    float c0[9], c1[9], c2[9];
    #pragma unroll
    for (int p = 0; p < 9; ++p) { c0[p] = 0.f; c1[p] = rp[p] ? rp[p][0] : 0.f; }
    size_t outbase = ((size_t)(n * 1600 + y * 40)) * 512 + m;
    for (int x = 0; x < 40; ++x) {
        #pragma unroll
        for (int p = 0; p < 9; ++p)
            c2[p] = (x < 39 && rp[p]) ? rp[p][(size_t)(x + 1) * 512] : 0.f;
        float acc = bs;
        #pragma unroll
        for (int p = 0; p < 9; ++p)
            acc += wr[p * 3 + 0] * c0[p] + wr[p * 3 + 1] * c1[p] + wr[p * 3 + 2] * c2[p];
        float g = 0.5f * acc * (1.0f + erff(acc * 0.70710678118654752f));
        outp[outbase + (size_t)x * 512] = __float2bfloat16(g);
        #pragma unroll
        for (int p = 0; p < 9; ++p) { c0[p] = c1[p]; c1[p] = c2[p]; }
    }
}

// ---- final LN + transpose to (b,c,t,y,x) fp32
__global__ __launch_bounds__(256) void k_ln_out(const float* __restrict__ src,
                                                const float* __restrict__ gamma,
                                                const float* __restrict__ beta,
                                                float* __restrict__ out) {
    int tok = blockIdx.x * 4 + (threadIdx.x >> 6);
    int lane = threadIdx.x & 63;
    float v0 = src[(size_t)tok * 128 + lane];
    float v1 = src[(size_t)tok * 128 + 64 + lane];
    float s = v0 + v1, q = v0 * v0 + v1 * v1;
    #pragma unroll
    for (int o = 32; o > 0; o >>= 1) { s += __shfl_xor(s, o); q += __shfl_xor(q, o); }
    float mean = s * (1.0f / 128.0f);
    float var = q * (1.0f / 128.0f) - mean * mean;
    float inv = rsqrtf(var + 1e-5f);
    float r0 = (v0 - mean) * inv * gamma[lane] + beta[lane];
    float r1 = (v1 - mean) * inv * gamma[64 + lane] + beta[64 + lane];
    int n = tok / 1600, rem = tok % 1600;
    int b = n >> 3, t = n & 7;
    out[((size_t)(b * 128 + lane) * 8 + t) * 1600 + rem] = r0;
    out[((size_t)(b * 128 + 64 + lane) * 8 + t) * 1600 + rem] = r1;
}

extern "C" void kernel_launch(void* const* d_in, const int* in_sizes, int n_in,
                              void* d_out, int out_size, void* d_ws, size_t ws_size,
                              hipStream_t stream) {
    const float* x      = (const float*)d_in[0];
    const float* ln1_g  = (const float*)d_in[1];
    const float* ln1_b  = (const float*)d_in[2];
    const float* qkv_w  = (const float*)d_in[3];
    const float* qkv_b  = (const float*)d_in[4];
    const float* rpb    = (const float*)d_in[5];
    const float* proj_w = (const float*)d_in[6];
    const float* proj_b = (const float*)d_in[7];
    const float* ln2_g  = (const float*)d_in[8];
    const float* ln2_b  = (const float*)d_in[9];
    const float* fc1_w  = (const float*)d_in[10];
    const float* fc1_b  = (const float*)d_in[11];
    const float* dw_w   = (const float*)d_in[12];
    const float* dw_b   = (const float*)d_in[13];
    const float* fc2_w  = (const float*)d_in[14];
    const float* fc2_b  = (const float*)d_in[15];
    const float* out_g  = (const float*)d_in[16];
    const float* out_b  = (const float*)d_in[17];
    float* out = (float*)d_out;

    // workspace layout:
    //  h    f32 NTOK*128
    //  qkvb f32 NTOK*384   (f2b bf16 NTOK*512 aliases this region; qkvb dead then)
    //  f1   f32 NTOK*512
    //  abuf bf16 NTOK*128  (LN out / attn out — GEMM A operand)
    //  wt   bf16 2*WT_L    (transposed weights)
    float* h    = (float*)d_ws;
    float* qkvb = h + (size_t)NTOK * 128;
    float* f1   = qkvb + (size_t)NTOK * 384;
    bf16* abuf  = (bf16*)(f1 + (size_t)NTOK * 512);
    bf16* wt    = abuf + (size_t)NTOK * 128;
    bf16* f2b   = (bf16*)qkvb;

    k_wt<<<96, 256, 0, stream>>>(qkv_w, proj_w, fc1_w, fc2_w, wt);
    k_transpose_in<<<NTOK * 128 / 256, 256, 0, stream>>>(x, h);
    for (int l = 0; l < 2; ++l) {
        const bf16* wtl = wt + (size_t)l * WT_L;
        k_ln<<<NTOK / 4, 256, 0, stream>>>(h, ln1_g + l * 128, ln1_b + l * 128, abuf);
        k_gemm_mfma<128, 128, 64, 64><<<dim3(3, 200), 256, 0, stream>>>(
            abuf, wtl + WT_QKV, qkv_b + l * 384, nullptr, qkvb, 128, 384);
        k_attn<<<NIMG * HH * NHEAD, 256, 0, stream>>>(qkvb, rpb + l * 4 * 169, abuf);
        k_gemm_mfma<64, 128, 32, 64><<<dim3(1, 400), 256, 0, stream>>>(
            abuf, wtl + WT_PROJ, proj_b + l * 128, h, h, 128, 128);
        k_ln<<<NTOK / 4, 256, 0, stream>>>(h, ln2_g + l * 128, ln2_b + l * 128, abuf);
        k_gemm_mfma<128, 128, 64, 64><<<dim3(4, 200), 256, 0, stream>>>(
            abuf, wtl + WT_FC1, fc1_b + l * 512, nullptr, f1, 128, 512);
        k_dwconv<<<NIMG * HH, 512, 0, stream>>>(f1, dw_w + l * 27 * 512, dw_b + l * 512, f2b);
        k_gemm_mfma<64, 128, 32, 64><<<dim3(1, 400), 256, 0, stream>>>(
            f2b, wtl + WT_FC2, fc2_b + l * 128, h, h, 512, 128);
    }
    k_ln_out<<<NTOK / 4, 256, 0, stream>>>(h, out_g, out_b, out);
}